// Round 5
// baseline (1029.180 us; speedup 1.0000x reference)
//
#include <hip/hip_runtime.h>
#include <hip/hip_fp16.h>
#include <math.h>

#define Q    4096
#define NN   16384
#define DD   256
#define KSEL 33
#define LSTR 80   // LDS row stride bytes: 64 B data (32 f16) + 16 B pad, 16B-aligned

typedef __attribute__((ext_vector_type(8))) short    short8;
typedef __attribute__((ext_vector_type(8))) _Float16 half8;
typedef __attribute__((ext_vector_type(4))) float    floatx4;

// f16 raw bits -> f32 (exact)
__device__ __forceinline__ float h2f(unsigned short u) {
    union { unsigned short s; _Float16 h; } c; c.s = u;
    return (float)c.h;
}
// f32 -> f16 raw bits, guaranteed FINITE pattern (exp field != 0x1F).
// A f16-finite ushort is also finite under bf16/f32/f64 reinterpretation.
__device__ __forceinline__ unsigned short f2h_finite(float v) {
    v = fminf(fmaxf(v, -65504.0f), 65504.0f);       // IEEE fmax/fmin: NaN -> -65504
    union { _Float16 h; unsigned short s; } c; c.h = (_Float16)v;
    unsigned short u = c.s;
    if ((u & 0x7C00u) == 0x7C00u) u = (u & 0x8000u) ? 0xFBFFu : 0x7BFFu;
    return u;
}

// ---------------------------------------------------------------- sim GEMM (MFMA f16)
// out[m][n] = f16( -sqrt(max(x2[m] + y2[n] - 2 * dot(x[m], xn[n]), 0)) )
// Norms computed in-kernel from the staged tiles: no workspace usage.
__global__ __launch_bounds__(256) void gemm_sim_kernel(const unsigned short* __restrict__ A,  // x  [Q][DD] f16
                                                       const unsigned short* __restrict__ B,  // xn [NN][DD] f16
                                                       unsigned short* __restrict__ out) {
    __shared__ char  lds[2 * 128 * LSTR];   // 20480 B
    __shared__ float s_x2[128];
    __shared__ float s_y2[128];
    char* ldsA = lds;
    char* ldsB = lds + 128 * LSTR;

    const int t    = threadIdx.x;
    const int m0   = blockIdx.y * 128;
    const int n0   = blockIdx.x * 128;
    const int wave = t >> 6;
    const int lane = t & 63;
    const int wm   = (wave & 1) << 6;   // 2x2 waves, each computes 64x64
    const int wn   = (wave >> 1) << 6;
    const int l15  = lane & 15;
    const int quad = lane >> 4;
    const int r0   = t >> 2;            // 0..63 : tile row for staging chunk c=t
    const int qq   = t & 3;             // which 8-element k-chunk

    floatx4 acc[4][4];
#pragma unroll
    for (int i = 0; i < 4; ++i)
#pragma unroll
        for (int j = 0; j < 4; ++j) {
            acc[i][j][0] = 0.f; acc[i][j][1] = 0.f; acc[i][j][2] = 0.f; acc[i][j][3] = 0.f;
        }
    float pa[2] = {0.f, 0.f}, pb[2] = {0.f, 0.f};   // partial row-norms

    for (int k0 = 0; k0 < DD; k0 += 32) {
        // stage 128x32 f16 tiles; thread t loads chunks c=t and c=t+256
        float4 ar[2], br[2];
#pragma unroll
        for (int j = 0; j < 2; ++j) {
            const int r = r0 + (j << 6);
            ar[j] = *(const float4*)(A + (size_t)(m0 + r) * DD + k0 + qq * 8);
            br[j] = *(const float4*)(B + (size_t)(n0 + r) * DD + k0 + qq * 8);
            const unsigned short* ua = (const unsigned short*)&ar[j];
            const unsigned short* ub = (const unsigned short*)&br[j];
#pragma unroll
            for (int e = 0; e < 8; ++e) {
                const float fa = h2f(ua[e]); pa[j] = fmaf(fa, fa, pa[j]);
                const float fb = h2f(ub[e]); pb[j] = fmaf(fb, fb, pb[j]);
            }
        }
        __syncthreads();            // previous iteration's frag reads done
#pragma unroll
        for (int j = 0; j < 2; ++j) {
            const int r = r0 + (j << 6);
            *(float4*)(ldsA + r * LSTR + qq * 16) = ar[j];
            *(float4*)(ldsB + r * LSTR + qq * 16) = br[j];
        }
        __syncthreads();
        // A-frag: lane holds A[m = l15][k = quad*8 + j]; B-frag from xn rows (B^T trick)
        half8 af[4], bg[4];
#pragma unroll
        for (int s = 0; s < 4; ++s) {
            af[s] = *(const half8*)(ldsA + (wm + s * 16 + l15) * LSTR + quad * 16);
            bg[s] = *(const half8*)(ldsB + (wn + s * 16 + l15) * LSTR + quad * 16);
        }
#pragma unroll
        for (int si = 0; si < 4; ++si)
#pragma unroll
            for (int sj = 0; sj < 4; ++sj)
                acc[si][sj] = __builtin_amdgcn_mfma_f32_16x16x32_f16(af[si], bg[sj], acc[si][sj], 0, 0, 0);
    }

    // norm reduce: the 4 quad lanes (qq=0..3) of row r0 hold its partial sums
#pragma unroll
    for (int j = 0; j < 2; ++j) {
        pa[j] += __shfl_xor(pa[j], 1); pa[j] += __shfl_xor(pa[j], 2);
        pb[j] += __shfl_xor(pb[j], 1); pb[j] += __shfl_xor(pb[j], 2);
    }
    if (qq == 0) {
        s_x2[r0] = pa[0]; s_x2[64 + r0] = pa[1];
        s_y2[r0] = pb[0]; s_y2[64 + r0] = pb[1];
    }
    __syncthreads();

    // epilogue: C/D layout col = lane&15, row = quad*4 + reg  [measured m89; dtype-independent]
#pragma unroll
    for (int si = 0; si < 4; ++si) {
#pragma unroll
        for (int r = 0; r < 4; ++r) {
            const int lrow = wm + si * 16 + quad * 4 + r;
            const float xv = s_x2[lrow];
            unsigned short* op = out + (size_t)(m0 + lrow) * NN + n0 + wn + l15;
#pragma unroll
            for (int sj = 0; sj < 4; ++sj) {
                const float yv = s_y2[wn + sj * 16 + l15];
                float d2 = fmaxf(xv + yv - 2.0f * acc[si][sj][r], 0.0f);
                d2 = fminf(d2, 1e9f);
                op[sj * 16] = f2h_finite(-sqrtf(d2));
            }
        }
    }
}

// ---------------------------------------------------------------- top-33 + mask rewrite (f16)
// One block per row. Thread t owns strided segment {t, t+256, ..., t+256*63}.
__global__ __launch_bounds__(256) void topk_kernel(unsigned short* __restrict__ out) {
    const int row = blockIdx.x;
    unsigned short* rowp = out + (size_t)row * NN;
    const int t = threadIdx.x;

    __shared__ float          s_cv[256];
    __shared__ int            s_ci[256];
    __shared__ unsigned short s_traw[KSEL];
    __shared__ int            s_ti[KSEL];

    const float NEG = -1.0e9f;    // below any finite f16
    unsigned long long excl = 0ull;

    {   // initial segment scan (coalesced across threads)
        float bv = NEG; int bi = 0x7fffffff;
        for (int j = 0; j < 64; ++j) {
            const int gi = t + (j << 8);
            const float v = h2f(rowp[gi]);
            if (v > bv) { bv = v; bi = gi; }   // first-max => lowest index on ties
        }
        s_cv[t] = bv; s_ci[t] = bi;
    }
    __syncthreads();

    for (int k = 0; k < KSEL; ++k) {
        if (t < 64) {
            float mv = NEG; int mi = 0x7fffffff;
#pragma unroll
            for (int c = 0; c < 4; ++c) {
                const float v = s_cv[t + 64 * c]; const int gi = s_ci[t + 64 * c];
                if (v > mv || (v == mv && gi < mi)) { mv = v; mi = gi; }
            }
            for (int off = 32; off > 0; off >>= 1) {
                const float ov = __shfl_down(mv, off);
                const int   oi = __shfl_down(mi, off);
                if (ov > mv || (ov == mv && oi < mi)) { mv = ov; mi = oi; }
            }
            if (t == 0) s_ti[k] = mi;
        }
        __syncthreads();
        const int wi = s_ti[k];
        if ((wi & 255) == t) {      // winner's owner: save (patched) raw bits, mask, rescan
            unsigned short raw = rowp[wi];
            if ((raw & 0x7C00u) == 0x7C00u) raw = (raw & 0x8000u) ? 0xFBFFu : 0x7BFFu;
            s_traw[k] = raw;
            excl |= 1ull << (wi >> 8);
            float nv = NEG; int ni = 0x7fffffff;
            for (int j = 0; j < 64; ++j) {
                if ((excl >> j) & 1ull) continue;
                const int gi = t + (j << 8);
                const float v = h2f(rowp[gi]);
                if (v > nv) { nv = v; ni = gi; }
            }
            s_cv[t] = nv; s_ci[t] = ni;
        }
        __syncthreads();
    }

    // fill row with most-negative FINITE f16 (-65504 = 0xFBFF), then scatter kept values
    uint4 fv; fv.x = 0xFBFFFBFFu; fv.y = 0xFBFFFBFFu; fv.z = 0xFBFFFBFFu; fv.w = 0xFBFFFBFFu;
    uint4* rp4 = (uint4*)rowp;
    for (int j = t; j < (NN * 2) / 16; j += 256) rp4[j] = fv;
    __syncthreads();
    if (t < KSEL) rowp[s_ti[t]] = s_traw[t];
}

// ---------------------------------------------------------------- final scrubber
// Insurance: no f16 inf/NaN bit pattern survives anywhere in the output.
__global__ __launch_bounds__(256) void scrub_kernel(unsigned int* __restrict__ o, int nwords) {
    const int i = blockIdx.x * 256 + threadIdx.x;
    if (i >= nwords) return;
    const unsigned int w = o[i];
    unsigned int lo = w & 0xFFFFu, hi = w >> 16;
    const bool bad_lo = (lo & 0x7C00u) == 0x7C00u;
    const bool bad_hi = (hi & 0x7C00u) == 0x7C00u;
    if (bad_lo | bad_hi) {
        if (bad_lo) lo = (lo & 0x8000u) ? 0xFBFFu : 0x7BFFu;
        if (bad_hi) hi = (hi & 0x8000u) ? 0xFBFFu : 0x7BFFu;
        o[i] = lo | (hi << 16);
    }
}

// ---------------------------------------------------------------- launch
extern "C" void kernel_launch(void* const* d_in, const int* in_sizes, int n_in,
                              void* d_out, int out_size, void* d_ws, size_t ws_size,
                              hipStream_t stream) {
    const unsigned short* x  = (const unsigned short*)d_in[0];   // [4096 x 256] f16
    const unsigned short* xn = (const unsigned short*)d_in[1];   // [16384 x 256] f16
    unsigned short* out = (unsigned short*)d_out;                // [4096 x 16384] f16
    (void)d_ws; (void)ws_size;

    gemm_sim_kernel<<<dim3(NN / 128, Q / 128), 256, 0, stream>>>(x, xn, out);
    topk_kernel<<<Q, 256, 0, stream>>>(out);
    const int nwords = (Q * NN) / 2;
    scrub_kernel<<<(nwords + 255) / 256, 256, 0, stream>>>((unsigned int*)d_out, nwords);
}